// Round 3
// baseline (320.521 us; speedup 1.0000x reference)
//
#include <hip/hip_runtime.h>
#include <stdint.h>

// out[ch][s] = sum_{v: sp[v]==s} x[ch][ht[v]] * w[v],  ch in [0,128)
//
// R1: atomic scatter wrote 768 MB -> bin by sphere (601us).
// R2: accum f32 gather bound -> bf16 xT (516us).
// R3: scatter 8B-random writes: 95MB amp + per-vote cursor atomics (115us).
// R4 FAILED (1532us): accum latency-bound (dependent global chains).
// R5 (409us): 1024-bucket sort + LDS-staged accum.
// R6 FAILED (absmax 17): epilogue cross-half LDS combine was an intra-wave race.
// R7 (317us): halves combined in REGISTERS via __shfl_xor(.,32).
// R8 NEUTRAL (315us): quarter-wave gather -> null => accum is LLC-BW/latency
//     bound (384 MB random 256B rows, 64 MB table), NOT issue-bound. Kept.
// R9 NEUTRAL (319us) but DIAGNOSTIC: fused transpose+reorder = 103us @ 21%
//     HBM, 14% VALU, 73% occ => latency-bound. 750K far-atomics into 64
//     cache lines (cursor[1024] ints, 16/line) ~= the whole 103us.
// R10: pad cursor to 1 counter / 64B line (1024 independent lines, ~733 ops
//     each in parallel) + replace 18-barrier scan with shfl wave-scan
//     (2 barriers). Predict fused 103 -> ~50us.

#define S_BINS   32768
#define NBUCKET  1024        // coarse buckets = s >> 5
#define BINS     32          // fine bins per bucket
#define CAP      2048        // record slots per bucket (mean 1465, +15 sigma)
#define CHUNK    2048        // votes per reorder block
#define HT_BITS  18          // HW = 512*512 = 2^18
#define CUR_STRIDE 16        // cursor padded to one int per 64B cache line

__device__ __forceinline__ unsigned bf16_rne(float f) {
    unsigned u = __float_as_uint(f);
    return (u + 0x7FFFu + ((u >> 16) & 1u)) >> 16;   // round-nearest-even
}

__global__ void init_kernel(int* __restrict__ cursor, int* __restrict__ spillCnt) {
    const int t = threadIdx.x;        // 1024
    cursor[t * CUR_STRIDE] = t * CAP;
    if (t == 0) *spillCnt = 0;
}

// Fused: blockIdx < nrb  -> reorder role (group CHUNK votes by bucket in LDS,
//                           one padded global cursor atomic per (block,bucket),
//                           dump grouped runs; record: x = ht | s_local<<18,
//                           y = w bits)
//        blockIdx >= nrb -> transpose role (x [128][HW] f32 -> xTb [HW][64]
//                           u32; word cp = bf16(ch=cp) | bf16(ch=cp+64)<<16)
// Roles are data-independent; fusing overlaps HBM-bound transpose with
// latency-bound reorder. Shared 38 KB LDS buffer (union of both layouts).
__global__ __launch_bounds__(512) void fused_tr_kernel(
    const float* __restrict__ x, uint32_t* __restrict__ xTb, int HW,
    const int* __restrict__ ht, const int* __restrict__ sp,
    const float* __restrict__ w, int* __restrict__ cursor,
    uint2* __restrict__ records, uint2* __restrict__ spillRec,
    int* __restrict__ spillBkt, int* __restrict__ spillCnt,
    int V, int nrb) {
    __shared__ __align__(16) char smem[38912];         // 38 KB -> 4 blk/CU
    const int t = threadIdx.x;                         // 512
    if ((int)blockIdx.x < nrb) {
        // ---------------- reorder role ----------------
        uint2*    rec   = (uint2*)smem;                // [2048]  16 KB
        uint16_t* bid   = (uint16_t*)(smem + 16384);   // [2048]   4 KB
        int*      hist  = (int*)(smem + 20480);        // [1024]   4 KB
        int*      start = (int*)(smem + 24576);        // [1024]   4 KB
        int*      cur   = (int*)(smem + 28672);        // [1024]   4 KB
        int*      gbase = (int*)(smem + 32768);        // [1024]   4 KB
        int*      wsum  = (int*)(smem + 36864);        // [8]     32 B
        const int blk = blockIdx.x;
        const int lane = t & 63, wv = t >> 6;          // 8 waves
        const int base = blk * CHUNK, end = min(V, base + CHUNK), n = end - base;
        hist[2 * t] = 0; hist[2 * t + 1] = 0;
        __syncthreads();
        for (int v = base + t; v < end; v += 512) atomicAdd(&hist[sp[v] >> 5], 1);
        __syncthreads();
        // exclusive scan of 1024 hist entries: shfl wave-scan, 2 barriers.
        // thread t owns buckets {2t, 2t+1}; wave wv owns buckets [128wv,128wv+128)
        const int l0 = hist[2 * t], l1 = hist[2 * t + 1];
        const int tot = l0 + l1;
        int sc = tot;                                   // inclusive within wave
#pragma unroll
        for (int off = 1; off < 64; off <<= 1) {
            const int up = __shfl_up(sc, off);
            if (lane >= off) sc += up;
        }
        if (lane == 63) wsum[wv] = sc;                  // wave totals
        __syncthreads();
        if (wv == 0 && lane < 8) {                      // exclusive scan of 8
            const int v0 = wsum[lane];
            int s = v0;
#pragma unroll
            for (int off = 1; off < 8; off <<= 1) {
                const int up = __shfl_up(s, off);
                if (lane >= off) s += up;
            }
            wsum[lane] = s - v0;
        }
        __syncthreads();
        int run = wsum[wv] + (sc - tot);                // global exclusive prefix
        start[2 * t]     = run; cur[2 * t]     = run; run += l0;
        start[2 * t + 1] = run; cur[2 * t + 1] = run;
        if (l0) gbase[2 * t]     = atomicAdd(&cursor[(2 * t)     * CUR_STRIDE], l0);
        if (l1) gbase[2 * t + 1] = atomicAdd(&cursor[(2 * t + 1) * CUR_STRIDE], l1);
        __syncthreads();
        for (int v = base + t; v < end; v += 512) {
            const int s = sp[v];
            const int b = s >> 5, sl = s & 31;
            const int pos = atomicAdd(&cur[b], 1);
            rec[pos] = make_uint2((unsigned)ht[v] | ((unsigned)sl << HT_BITS),
                                  __float_as_uint(w[v]));
            bid[pos] = (uint16_t)b;
        }
        __syncthreads();
        for (int i = t; i < n; i += 512) {
            const int b = bid[i];
            const int slot = gbase[b] + (i - start[b]);
            if (slot < (b + 1) * CAP) {
                records[slot] = rec[i];
            } else {                                    // overflow: spill (cold)
                const int pos = atomicAdd(spillCnt, 1);
                spillRec[pos] = rec[i];
                spillBkt[pos] = b;
            }
        }
    } else {
        // ---------------- transpose role ----------------
        float* tile = (float*)smem;                     // [64][129] 33 KB
        const int ht0 = ((int)blockIdx.x - nrb) * 64;
        for (int e = t; e < 128 * 64; e += 512) {
            const int ch = e >> 6, hl = e & 63;
            tile[hl * 129 + ch] = x[(size_t)ch * HW + ht0 + hl];
        }
        __syncthreads();
        for (int e = t; e < 64 * 64; e += 512) {
            const int hl = e >> 6, cp = e & 63;
            const unsigned lo = bf16_rne(tile[hl * 129 + cp]);
            const unsigned hi = bf16_rne(tile[hl * 129 + cp + 64]);
            xTb[(size_t)(ht0 + hl) * 64 + cp] = lo | (hi << 16);
        }
    }
}

// One block per bucket, 8 waves x 64 lanes. Records staged+fine-sorted in LDS
// (32 bins); wave owns 4 bins; QUARTER-WAVE processes one vote (lane ql loads
// dwordx4 = words {4ql..4ql+3} = channels {4ql..4ql+3, 4ql+64..4ql+67});
// 4 votes per wave-load-instruction. Quarters combined via shfl_xor(16) then
// shfl_xor(32) in registers (race-free); lanes 0..15 write epilogue LDS.
// Spilled votes (cold, cnt ~0) folded in before the out write.
__global__ __launch_bounds__(512) void accum_kernel(
    const uint32_t* __restrict__ xTb, const uint2* __restrict__ records,
    const int* __restrict__ cursor, const uint2* __restrict__ spillRec,
    const int* __restrict__ spillBkt, const int* __restrict__ spillCnt,
    float* __restrict__ out) {
    __shared__ uint2 sorted[CAP];                        // 16 KB
    __shared__ __align__(16) char rawbuf[BINS * 129 * 4];// 16.5 KB raw/epilogue
    __shared__ int hist[BINS], off[BINS + 1], cur[BINS];
    uint2* raw = (uint2*)rawbuf;
    const uint4* xTb4 = (const uint4*)xTb;               // [HW][16] uint4 rows
    const int bkt = blockIdx.x, t = threadIdx.x;
    const int lane = t & 63, wv = t >> 6;                // 8 waves
    const int q = lane >> 4, ql = lane & 15;             // quarter-wave id/lane
    const int n = min(cursor[bkt * CUR_STRIDE] - bkt * CAP, CAP);
    const int rbase = bkt * CAP;
    float a[4][8];
#pragma unroll
    for (int i = 0; i < 4; ++i)
#pragma unroll
        for (int j = 0; j < 8; ++j) a[i][j] = 0.f;

    if (t < BINS) hist[t] = 0;
    __syncthreads();
    for (int i = t; i < n; i += 512) {                   // stage + histogram
        const uint2 r = records[rbase + i];
        raw[i] = r;
        atomicAdd(&hist[(r.x >> HT_BITS) & 31], 1);
    }
    __syncthreads();
    if (t == 0) {                                        // tiny 32-entry scan
        int run = 0;
        for (int j = 0; j < BINS; ++j) { off[j] = run; cur[j] = run; run += hist[j]; }
        off[BINS] = run;
    }
    __syncthreads();
    for (int i = t; i < n; i += 512) {                   // place sorted
        const uint2 r = raw[i];
        const int pos = atomicAdd(&cur[(r.x >> HT_BITS) & 31], 1);
        sorted[pos] = r;
    }
    __syncthreads();
#pragma unroll
    for (int bb = 0; bb < 4; ++bb) {                     // wave-uniform control
        const int f = wv * 4 + bb;
        const int s0 = off[f], s1 = off[f + 1];
#pragma unroll 1
        for (int k = s0; k < s1; k += 16) {              // 4-deep x 4 votes
#pragma unroll
            for (int u = 0; u < 4; ++u) {
                const int kk = k + 4 * u + q;
                if (kk < s1) {
                    const uint2 r = sorted[kk];          // 4-addr LDS broadcast
                    const uint4 g = xTb4[(size_t)(r.x & 0x3FFFF) * 16 + ql];
                    const float wt = __uint_as_float(r.y);
                    a[bb][0] += __uint_as_float(g.x << 16)          * wt;
                    a[bb][1] += __uint_as_float(g.x & 0xFFFF0000u)  * wt;
                    a[bb][2] += __uint_as_float(g.y << 16)          * wt;
                    a[bb][3] += __uint_as_float(g.y & 0xFFFF0000u)  * wt;
                    a[bb][4] += __uint_as_float(g.z << 16)          * wt;
                    a[bb][5] += __uint_as_float(g.z & 0xFFFF0000u)  * wt;
                    a[bb][6] += __uint_as_float(g.w << 16)          * wt;
                    a[bb][7] += __uint_as_float(g.w & 0xFFFF0000u)  * wt;
                }
            }
        }
    }
    // combine quarter-waves in registers: lane^16 then lane^32 (race-free)
#pragma unroll
    for (int bb = 0; bb < 4; ++bb)
#pragma unroll
        for (int j = 0; j < 8; ++j) {
            a[bb][j] += __shfl_xor(a[bb][j], 16);
            a[bb][j] += __shfl_xor(a[bb][j], 32);
        }
    __syncthreads();                                     // before LDS reuse
    // epilogue: lanes 0..15 hold full sums -> LDS -> out rows (128B runs)
    float* epi = (float*)rawbuf;                         // [32][129]
    if (lane < 16) {
#pragma unroll
        for (int bb = 0; bb < 4; ++bb) {
            const int f = wv * 4 + bb;
            epi[f * 129 + 4 * ql]      = a[bb][0];
            epi[f * 129 + 4 * ql + 64] = a[bb][1];
            epi[f * 129 + 4 * ql + 1]  = a[bb][2];
            epi[f * 129 + 4 * ql + 65] = a[bb][3];
            epi[f * 129 + 4 * ql + 2]  = a[bb][4];
            epi[f * 129 + 4 * ql + 66] = a[bb][5];
            epi[f * 129 + 4 * ql + 3]  = a[bb][6];
            epi[f * 129 + 4 * ql + 67] = a[bb][7];
        }
    }
    __syncthreads();
    // folded spill handling (cold: cnt ~ 0; uniform branch, no divergence)
    const int cnt = *spillCnt;
    if (cnt > 0) {
        const uint2* xTb2 = (const uint2*)xTb;
        const int hl = lane & 31;                        // half-wave per spill
        for (int i = t >> 5; i < cnt; i += 16) {
            if (spillBkt[i] == bkt) {
                const uint2 r = spillRec[i];
                const int f = (r.x >> HT_BITS) & 31;
                const uint2 g = xTb2[(size_t)(r.x & 0x3FFFF) * 32 + hl];
                const float wt = __uint_as_float(r.y);
                atomicAdd(&epi[f * 129 + 2 * hl],
                          __uint_as_float(g.x << 16) * wt);
                atomicAdd(&epi[f * 129 + 2 * hl + 64],
                          __uint_as_float(g.x & 0xFFFF0000u) * wt);
                atomicAdd(&epi[f * 129 + 2 * hl + 1],
                          __uint_as_float(g.y << 16) * wt);
                atomicAdd(&epi[f * 129 + 2 * hl + 65],
                          __uint_as_float(g.y & 0xFFFF0000u) * wt);
            }
        }
        __syncthreads();
    }
    for (int i = t; i < 128 * BINS; i += 512) {
        const int ch = i >> 5, bin = i & 31;
        out[(size_t)ch * S_BINS + bkt * BINS + bin] = epi[bin * 129 + ch];
    }
}

// ---- fallback (direct atomic, any shape) ----
__global__ void direct_kernel(const float* __restrict__ x,
                              const int* __restrict__ ht_idx,
                              const int* __restrict__ sp_idx,
                              const float* __restrict__ weight,
                              float* __restrict__ out, int V, int HW, int S,
                              int CH) {
    const int v = blockIdx.x * 2 + (threadIdx.x >> 7);
    if (v >= V) return;
    const int ch = threadIdx.x & 127;
    if (ch >= CH) return;
    atomicAdd(&out[(size_t)ch * S + sp_idx[v]],
              x[(size_t)ch * HW + ht_idx[v]] * weight[v]);
}

extern "C" void kernel_launch(void* const* d_in, const int* in_sizes, int n_in,
                              void* d_out, int out_size, void* d_ws, size_t ws_size,
                              hipStream_t stream) {
    const float* x  = (const float*)d_in[0];
    const int*   ht = (const int*)d_in[1];
    const int*   sp = (const int*)d_in[2];
    const float* w  = (const float*)d_in[3];
    float* out = (float*)d_out;

    const int HW = 512 * 512;
    const int CH = in_sizes[0] / HW;          // 128
    const int S  = out_size / CH;             // 32768
    const int V  = in_sizes[1];               // 1.5M
    const int nrb = (V + CHUNK - 1) / CHUNK;  // 733 reorder-role blocks
    const int ntb = HW / 64;                  // 4096 transpose-role blocks

    const size_t xTb_bytes = (size_t)CH * HW * sizeof(uint16_t);    // 64 MB
    const size_t rec_bytes = (size_t)NBUCKET * CAP * sizeof(uint2); // 16 MB
    const size_t spr_bytes = (size_t)V * sizeof(uint2);             // 12 MB
    const size_t spb_bytes = (size_t)V * sizeof(int);               // 6 MB
    const size_t cur_bytes = (size_t)NBUCKET * CUR_STRIDE * sizeof(int); // 64 KB
    const size_t cnt_bytes = 64;
    const size_t need = xTb_bytes + rec_bytes + spr_bytes + spb_bytes +
                        cur_bytes + cnt_bytes;

    if (CH == 128 && S == S_BINS && HW == (1 << HT_BITS) && ws_size >= need) {
        char* p = (char*)d_ws;
        uint32_t* xTb  = (uint32_t*)p;  p += xTb_bytes;
        uint2* records = (uint2*)p;     p += rec_bytes;
        uint2* spillRec= (uint2*)p;     p += spr_bytes;
        int* spillBkt  = (int*)p;       p += spb_bytes;
        int* cursor    = (int*)p;       p += cur_bytes;
        int* spillCnt  = (int*)p;

        init_kernel<<<1, NBUCKET, 0, stream>>>(cursor, spillCnt);
        fused_tr_kernel<<<nrb + ntb, 512, 0, stream>>>(
            x, xTb, HW, ht, sp, w, cursor, records, spillRec, spillBkt,
            spillCnt, V, nrb);
        accum_kernel<<<NBUCKET, 512, 0, stream>>>(xTb, records, cursor,
                                                  spillRec, spillBkt, spillCnt,
                                                  out);
    } else {
        hipMemsetAsync(out, 0, (size_t)out_size * sizeof(float), stream);
        direct_kernel<<<(V + 1) / 2, 256, 0, stream>>>(x, ht, sp, w, out, V, HW,
                                                       S, CH);
    }
}

// Round 4
// 299.446 us; speedup vs baseline: 1.0704x; 1.0704x over previous
//
#include <hip/hip_runtime.h>
#include <stdint.h>

// out[ch][s] = sum_{v: sp[v]==s} x[ch][ht[v]] * w[v],  ch in [0,128)
//
// R1: atomic scatter wrote 768 MB -> bin by sphere (601us).
// R2: accum f32 gather bound -> bf16 xT (516us).
// R3: scatter 8B-random writes: 95MB amp + per-vote cursor atomics (115us).
// R4 FAILED (1532us): accum latency-bound (dependent global chains).
// R5 (409us): 1024-bucket sort + LDS-staged accum.
// R6 FAILED (absmax 17): epilogue cross-half LDS combine was an intra-wave race.
// R7 (317us): halves combined in REGISTERS via __shfl_xor(.,32).
// R8 NEUTRAL (315us): quarter-wave gather -> null => accum is LLC-BW/latency
//     bound (384 MB random 256B rows, 64 MB table), NOT issue-bound. Kept.
// R9 NEUTRAL (319us) but DIAGNOSTIC: fused transpose+reorder = 103us @ 21%
//     HBM, 14% VALU, 73% occ => latency-bound.
// R10 NULL (320us): cursor padded to 1/line -> no change. Atomics exonerated.
//     WRITE_SIZE 112MB vs ~76MB useful => scatter partial-line RMW is the
//     remaining suspect: CHUNK=2048 made runs 2 rec = 16B of a random cold
//     64B line (733K runs ~ 48MB line-RMW).
// R11: CHUNK=8192 -> runs avg 8 rec = 64B (full line), 188K runs, 4x fewer
//     atomics. LDS refit: drop bid/start/psum; bucket-of-i recovered by
//     10-step binary search over cur[] (end offsets); start = cur[b-1].
//     76KB LDS -> 2 blk/CU.

#define S_BINS   32768
#define NBUCKET  1024        // coarse buckets = s >> 5
#define BINS     32          // fine bins per bucket
#define CAP      2048        // record slots per bucket (mean 1465, +15 sigma)
#define CHUNK    8192        // votes per reorder block
#define HT_BITS  18          // HW = 512*512 = 2^18
#define CUR_STRIDE 16        // cursor padded to one int per 64B cache line

__device__ __forceinline__ unsigned bf16_rne(float f) {
    unsigned u = __float_as_uint(f);
    return (u + 0x7FFFu + ((u >> 16) & 1u)) >> 16;   // round-nearest-even
}

__global__ void init_kernel(int* __restrict__ cursor, int* __restrict__ spillCnt) {
    const int t = threadIdx.x;        // 1024
    cursor[t * CUR_STRIDE] = t * CAP;
    if (t == 0) *spillCnt = 0;
}

// Fused: blockIdx < nrb  -> reorder role (group CHUNK votes by bucket in LDS,
//                           one padded global cursor atomic per (block,bucket),
//                           dump grouped full-line runs; record:
//                           x = ht | s_local<<18, y = w bits)
//        blockIdx >= nrb -> transpose role (x [128][HW] f32 -> xTb [HW][64]
//                           u32; word cp = bf16(ch=cp) | bf16(ch=cp+64)<<16)
// Roles are data-independent; fusing overlaps HBM-bound transpose with
// latency-bound reorder. Shared 76 KB LDS buffer (union of both layouts).
__global__ __launch_bounds__(512) void fused_tr_kernel(
    const float* __restrict__ x, uint32_t* __restrict__ xTb, int HW,
    const int* __restrict__ ht, const int* __restrict__ sp,
    const float* __restrict__ w, int* __restrict__ cursor,
    uint2* __restrict__ records, uint2* __restrict__ spillRec,
    int* __restrict__ spillBkt, int* __restrict__ spillCnt,
    int V, int nrb) {
    __shared__ __align__(16) char smem[77888];         // 76 KB -> 2 blk/CU
    const int t = threadIdx.x;                         // 512
    if ((int)blockIdx.x < nrb) {
        // ---------------- reorder role ----------------
        uint2* rec   = (uint2*)smem;                   // [8192] 64 KB
        int*   hist  = (int*)(smem + 65536);           // [1024]  4 KB
        int*   cur   = (int*)(smem + 69632);           // [1024]  4 KB
        int*   gbase = (int*)(smem + 73728);           // [1024]  4 KB
        int*   wsum  = (int*)(smem + 77824);           // [8]    32 B
        const int blk = blockIdx.x;
        const int lane = t & 63, wv = t >> 6;          // 8 waves
        const int base = blk * CHUNK, end = min(V, base + CHUNK), n = end - base;
        hist[2 * t] = 0; hist[2 * t + 1] = 0;
        __syncthreads();
        for (int v = base + t; v < end; v += 512) atomicAdd(&hist[sp[v] >> 5], 1);
        __syncthreads();
        // exclusive scan of 1024 hist entries: shfl wave-scan, 2 barriers.
        // thread t owns buckets {2t, 2t+1}; wave wv owns buckets [128wv,128wv+128)
        const int l0 = hist[2 * t], l1 = hist[2 * t + 1];
        const int tot = l0 + l1;
        int sc = tot;                                   // inclusive within wave
#pragma unroll
        for (int off = 1; off < 64; off <<= 1) {
            const int up = __shfl_up(sc, off);
            if (lane >= off) sc += up;
        }
        if (lane == 63) wsum[wv] = sc;                  // wave totals
        __syncthreads();
        if (wv == 0 && lane < 8) {                      // exclusive scan of 8
            const int v0 = wsum[lane];
            int s = v0;
#pragma unroll
            for (int off = 1; off < 8; off <<= 1) {
                const int up = __shfl_up(s, off);
                if (lane >= off) s += up;
            }
            wsum[lane] = s - v0;
        }
        __syncthreads();
        const int run = wsum[wv] + (sc - tot);          // global exclusive prefix
        cur[2 * t]     = run;
        cur[2 * t + 1] = run + l0;
        if (l0) gbase[2 * t]     = atomicAdd(&cursor[(2 * t)     * CUR_STRIDE], l0);
        if (l1) gbase[2 * t + 1] = atomicAdd(&cursor[(2 * t + 1) * CUR_STRIDE], l1);
        __syncthreads();
        for (int v = base + t; v < end; v += 512) {
            const int s = sp[v];
            const int b = s >> 5, sl = s & 31;
            const int pos = atomicAdd(&cur[b], 1);
            rec[pos] = make_uint2((unsigned)ht[v] | ((unsigned)sl << HT_BITS),
                                  __float_as_uint(w[v]));
        }
        __syncthreads();
        // now cur[b] = end offset of bucket b (sorted); start[b] = cur[b-1]
        for (int i = t; i < n; i += 512) {
            int lo = 0, hi = NBUCKET - 1;               // upper_bound(cur, i)
#pragma unroll
            for (int it = 0; it < 10; ++it) {
                const int mid = (lo + hi) >> 1;
                if (i < cur[mid]) hi = mid; else lo = mid + 1;
            }
            const int b = lo;
            const int sb = (b == 0) ? 0 : cur[b - 1];
            const int slot = gbase[b] + (i - sb);
            if (slot < (b + 1) * CAP) {
                records[slot] = rec[i];
            } else {                                    // overflow: spill (cold)
                const int pos = atomicAdd(spillCnt, 1);
                spillRec[pos] = rec[i];
                spillBkt[pos] = b;
            }
        }
    } else {
        // ---------------- transpose role ----------------
        float* tile = (float*)smem;                     // [64][129] 33 KB
        const int ht0 = ((int)blockIdx.x - nrb) * 64;
        for (int e = t; e < 128 * 64; e += 512) {
            const int ch = e >> 6, hl = e & 63;
            tile[hl * 129 + ch] = x[(size_t)ch * HW + ht0 + hl];
        }
        __syncthreads();
        for (int e = t; e < 64 * 64; e += 512) {
            const int hl = e >> 6, cp = e & 63;
            const unsigned lo = bf16_rne(tile[hl * 129 + cp]);
            const unsigned hi = bf16_rne(tile[hl * 129 + cp + 64]);
            xTb[(size_t)(ht0 + hl) * 64 + cp] = lo | (hi << 16);
        }
    }
}

// One block per bucket, 8 waves x 64 lanes. Records staged+fine-sorted in LDS
// (32 bins); wave owns 4 bins; QUARTER-WAVE processes one vote (lane ql loads
// dwordx4 = words {4ql..4ql+3} = channels {4ql..4ql+3, 4ql+64..4ql+67});
// 4 votes per wave-load-instruction. Quarters combined via shfl_xor(16) then
// shfl_xor(32) in registers (race-free); lanes 0..15 write epilogue LDS.
// Spilled votes (cold, cnt ~0) folded in before the out write.
__global__ __launch_bounds__(512) void accum_kernel(
    const uint32_t* __restrict__ xTb, const uint2* __restrict__ records,
    const int* __restrict__ cursor, const uint2* __restrict__ spillRec,
    const int* __restrict__ spillBkt, const int* __restrict__ spillCnt,
    float* __restrict__ out) {
    __shared__ uint2 sorted[CAP];                        // 16 KB
    __shared__ __align__(16) char rawbuf[BINS * 129 * 4];// 16.5 KB raw/epilogue
    __shared__ int hist[BINS], off[BINS + 1], cur[BINS];
    uint2* raw = (uint2*)rawbuf;
    const uint4* xTb4 = (const uint4*)xTb;               // [HW][16] uint4 rows
    const int bkt = blockIdx.x, t = threadIdx.x;
    const int lane = t & 63, wv = t >> 6;                // 8 waves
    const int q = lane >> 4, ql = lane & 15;             // quarter-wave id/lane
    const int n = min(cursor[bkt * CUR_STRIDE] - bkt * CAP, CAP);
    const int rbase = bkt * CAP;
    float a[4][8];
#pragma unroll
    for (int i = 0; i < 4; ++i)
#pragma unroll
        for (int j = 0; j < 8; ++j) a[i][j] = 0.f;

    if (t < BINS) hist[t] = 0;
    __syncthreads();
    for (int i = t; i < n; i += 512) {                   // stage + histogram
        const uint2 r = records[rbase + i];
        raw[i] = r;
        atomicAdd(&hist[(r.x >> HT_BITS) & 31], 1);
    }
    __syncthreads();
    if (t == 0) {                                        // tiny 32-entry scan
        int run = 0;
        for (int j = 0; j < BINS; ++j) { off[j] = run; cur[j] = run; run += hist[j]; }
        off[BINS] = run;
    }
    __syncthreads();
    for (int i = t; i < n; i += 512) {                   // place sorted
        const uint2 r = raw[i];
        const int pos = atomicAdd(&cur[(r.x >> HT_BITS) & 31], 1);
        sorted[pos] = r;
    }
    __syncthreads();
#pragma unroll
    for (int bb = 0; bb < 4; ++bb) {                     // wave-uniform control
        const int f = wv * 4 + bb;
        const int s0 = off[f], s1 = off[f + 1];
#pragma unroll 1
        for (int k = s0; k < s1; k += 16) {              // 4-deep x 4 votes
#pragma unroll
            for (int u = 0; u < 4; ++u) {
                const int kk = k + 4 * u + q;
                if (kk < s1) {
                    const uint2 r = sorted[kk];          // 4-addr LDS broadcast
                    const uint4 g = xTb4[(size_t)(r.x & 0x3FFFF) * 16 + ql];
                    const float wt = __uint_as_float(r.y);
                    a[bb][0] += __uint_as_float(g.x << 16)          * wt;
                    a[bb][1] += __uint_as_float(g.x & 0xFFFF0000u)  * wt;
                    a[bb][2] += __uint_as_float(g.y << 16)          * wt;
                    a[bb][3] += __uint_as_float(g.y & 0xFFFF0000u)  * wt;
                    a[bb][4] += __uint_as_float(g.z << 16)          * wt;
                    a[bb][5] += __uint_as_float(g.z & 0xFFFF0000u)  * wt;
                    a[bb][6] += __uint_as_float(g.w << 16)          * wt;
                    a[bb][7] += __uint_as_float(g.w & 0xFFFF0000u)  * wt;
                }
            }
        }
    }
    // combine quarter-waves in registers: lane^16 then lane^32 (race-free)
#pragma unroll
    for (int bb = 0; bb < 4; ++bb)
#pragma unroll
        for (int j = 0; j < 8; ++j) {
            a[bb][j] += __shfl_xor(a[bb][j], 16);
            a[bb][j] += __shfl_xor(a[bb][j], 32);
        }
    __syncthreads();                                     // before LDS reuse
    // epilogue: lanes 0..15 hold full sums -> LDS -> out rows (128B runs)
    float* epi = (float*)rawbuf;                         // [32][129]
    if (lane < 16) {
#pragma unroll
        for (int bb = 0; bb < 4; ++bb) {
            const int f = wv * 4 + bb;
            epi[f * 129 + 4 * ql]      = a[bb][0];
            epi[f * 129 + 4 * ql + 64] = a[bb][1];
            epi[f * 129 + 4 * ql + 1]  = a[bb][2];
            epi[f * 129 + 4 * ql + 65] = a[bb][3];
            epi[f * 129 + 4 * ql + 2]  = a[bb][4];
            epi[f * 129 + 4 * ql + 66] = a[bb][5];
            epi[f * 129 + 4 * ql + 3]  = a[bb][6];
            epi[f * 129 + 4 * ql + 67] = a[bb][7];
        }
    }
    __syncthreads();
    // folded spill handling (cold: cnt ~ 0; uniform branch, no divergence)
    const int cnt = *spillCnt;
    if (cnt > 0) {
        const uint2* xTb2 = (const uint2*)xTb;
        const int hl = lane & 31;                        // half-wave per spill
        for (int i = t >> 5; i < cnt; i += 16) {
            if (spillBkt[i] == bkt) {
                const uint2 r = spillRec[i];
                const int f = (r.x >> HT_BITS) & 31;
                const uint2 g = xTb2[(size_t)(r.x & 0x3FFFF) * 32 + hl];
                const float wt = __uint_as_float(r.y);
                atomicAdd(&epi[f * 129 + 2 * hl],
                          __uint_as_float(g.x << 16) * wt);
                atomicAdd(&epi[f * 129 + 2 * hl + 64],
                          __uint_as_float(g.x & 0xFFFF0000u) * wt);
                atomicAdd(&epi[f * 129 + 2 * hl + 1],
                          __uint_as_float(g.y << 16) * wt);
                atomicAdd(&epi[f * 129 + 2 * hl + 65],
                          __uint_as_float(g.y & 0xFFFF0000u) * wt);
            }
        }
        __syncthreads();
    }
    for (int i = t; i < 128 * BINS; i += 512) {
        const int ch = i >> 5, bin = i & 31;
        out[(size_t)ch * S_BINS + bkt * BINS + bin] = epi[bin * 129 + ch];
    }
}

// ---- fallback (direct atomic, any shape) ----
__global__ void direct_kernel(const float* __restrict__ x,
                              const int* __restrict__ ht_idx,
                              const int* __restrict__ sp_idx,
                              const float* __restrict__ weight,
                              float* __restrict__ out, int V, int HW, int S,
                              int CH) {
    const int v = blockIdx.x * 2 + (threadIdx.x >> 7);
    if (v >= V) return;
    const int ch = threadIdx.x & 127;
    if (ch >= CH) return;
    atomicAdd(&out[(size_t)ch * S + sp_idx[v]],
              x[(size_t)ch * HW + ht_idx[v]] * weight[v]);
}

extern "C" void kernel_launch(void* const* d_in, const int* in_sizes, int n_in,
                              void* d_out, int out_size, void* d_ws, size_t ws_size,
                              hipStream_t stream) {
    const float* x  = (const float*)d_in[0];
    const int*   ht = (const int*)d_in[1];
    const int*   sp = (const int*)d_in[2];
    const float* w  = (const float*)d_in[3];
    float* out = (float*)d_out;

    const int HW = 512 * 512;
    const int CH = in_sizes[0] / HW;          // 128
    const int S  = out_size / CH;             // 32768
    const int V  = in_sizes[1];               // 1.5M
    const int nrb = (V + CHUNK - 1) / CHUNK;  // 184 reorder-role blocks
    const int ntb = HW / 64;                  // 4096 transpose-role blocks

    const size_t xTb_bytes = (size_t)CH * HW * sizeof(uint16_t);    // 64 MB
    const size_t rec_bytes = (size_t)NBUCKET * CAP * sizeof(uint2); // 16 MB
    const size_t spr_bytes = (size_t)V * sizeof(uint2);             // 12 MB
    const size_t spb_bytes = (size_t)V * sizeof(int);               // 6 MB
    const size_t cur_bytes = (size_t)NBUCKET * CUR_STRIDE * sizeof(int); // 64 KB
    const size_t cnt_bytes = 64;
    const size_t need = xTb_bytes + rec_bytes + spr_bytes + spb_bytes +
                        cur_bytes + cnt_bytes;

    if (CH == 128 && S == S_BINS && HW == (1 << HT_BITS) && ws_size >= need) {
        char* p = (char*)d_ws;
        uint32_t* xTb  = (uint32_t*)p;  p += xTb_bytes;
        uint2* records = (uint2*)p;     p += rec_bytes;
        uint2* spillRec= (uint2*)p;     p += spr_bytes;
        int* spillBkt  = (int*)p;       p += spb_bytes;
        int* cursor    = (int*)p;       p += cur_bytes;
        int* spillCnt  = (int*)p;

        init_kernel<<<1, NBUCKET, 0, stream>>>(cursor, spillCnt);
        fused_tr_kernel<<<nrb + ntb, 512, 0, stream>>>(
            x, xTb, HW, ht, sp, w, cursor, records, spillRec, spillBkt,
            spillCnt, V, nrb);
        accum_kernel<<<NBUCKET, 512, 0, stream>>>(xTb, records, cursor,
                                                  spillRec, spillBkt, spillCnt,
                                                  out);
    } else {
        hipMemsetAsync(out, 0, (size_t)out_size * sizeof(float), stream);
        direct_kernel<<<(V + 1) / 2, 256, 0, stream>>>(x, ht, sp, w, out, V, HW,
                                                       S, CH);
    }
}